// Round 3
// baseline (469.996 us; speedup 1.0000x reference)
//
#include <hip/hip_runtime.h>
#include <hip/hip_fp16.h>

typedef int v4i __attribute__((ext_vector_type(4)));

#define AS1C(p) ((const __attribute__((address_space(1))) void*)(p))
#define AS3(p)  ((__attribute__((address_space(3))) void*)(p))

#define BARRIER() do { __builtin_amdgcn_s_barrier(); asm volatile("" ::: "memory"); } while (0)

// ---------------------------------------------------------------------------
// 256x256 int8 GEMM, C = A[M,K] * B[N,K]^T, 8 waves (2M x 4N), BK=64 bytes,
// mfma_i32_16x16x64_i8, 3-buffer LDS ring, depth-2 prefetch, counted vmcnt,
// 4 phases per K-tile with per-phase barriers + setprio around MFMA clusters.
// LDS 16B-slot XOR swizzle (involution, verified 0 bank conflicts in r2).
// EPI 0: fc1 (dequant+bias -> fp16 -> GELU -> gout fp16 + atomicMax amax)
// EPI 1: fc2 (dequant with fp16(amax/127)+bias -> fp16-rounded f32 out)
// ---------------------------------------------------------------------------
template <int EPI>
__launch_bounds__(512, 2)
__global__ void gemm_i8_big(const signed char* __restrict__ A, const signed char* __restrict__ Bw,
                            int M, int N, int K,
                            const float* __restrict__ scale_tok, const float* __restrict__ wsc,
                            const float* __restrict__ bias,
                            __half* __restrict__ gout, unsigned int* __restrict__ amax,
                            float* __restrict__ fout) {
  __shared__ __align__(16) char smem[3][32768];   // per buf: A 16KB | B 16KB
  const int tid = threadIdx.x;
  const int lane = tid & 63, wave = tid >> 6;
  const int wavem = wave >> 2, waven = wave & 3;
  const long long t0 = (long long)blockIdx.y * 256;
  const long long n0 = (long long)blockIdx.x * 256;
  const int nk = K >> 6;

  // ---- staging addresses (global side carries the slot XOR; LDS is linear)
  const int gs = (((lane & 3) ^ ((lane >> 3) & 3)) << 4);
  long long rA0 = t0 + wave * 32 + (lane >> 2);
  long long rA1 = rA0 + 16;
  rA0 = rA0 > (long long)M - 1 ? (long long)M - 1 : rA0;
  rA1 = rA1 > (long long)M - 1 ? (long long)M - 1 : rA1;
  long long rB0 = n0 + wave * 32 + (lane >> 2);
  long long rB1 = rB0 + 16;
  rB0 = rB0 > (long long)N - 1 ? (long long)N - 1 : rB0;
  rB1 = rB1 > (long long)N - 1 ? (long long)N - 1 : rB1;
  const signed char* pa0 = A + rA0 * K + gs;
  const signed char* pa1 = A + rA1 * K + gs;
  const signed char* pb0 = Bw + rB0 * K + gs;
  const signed char* pb1 = Bw + rB1 * K + gs;
  const int dstA = wave * 2048;                 // chunks wave*2, wave*2+1

#define STAGE_A(kk, bufi) do { \
    __builtin_amdgcn_global_load_lds(AS1C(pa0 + (kk)), AS3(&smem[bufi][dstA]), 16, 0, 0); \
    __builtin_amdgcn_global_load_lds(AS1C(pa1 + (kk)), AS3(&smem[bufi][dstA + 1024]), 16, 0, 0); \
  } while (0)
#define STAGE_B(kk, bufi) do { \
    __builtin_amdgcn_global_load_lds(AS1C(pb0 + (kk)), AS3(&smem[bufi][16384 + dstA]), 16, 0, 0); \
    __builtin_amdgcn_global_load_lds(AS1C(pb1 + (kk)), AS3(&smem[bufi][16384 + dstA + 1024]), 16, 0, 0); \
  } while (0)

  // ---- reader offsets (same XOR involution; 2-way conflict = free)
  const int lh = lane & 15;
  const int slot = (((lane >> 4) ^ ((lh >> 1) & 3)) << 4);
  const int offA = wavem * 8192 + lh * 64 + slot;
  const int offB = 16384 + waven * 4096 + lh * 64 + slot;

  v4i acc[8][4] = {};
  v4i a_[8], b_[4];

  // ---- prologue: stage tiles 0,1; drain tile 0
  STAGE_A(0, 0); STAGE_B(0, 0);
  if (nk > 1) {
    STAGE_A(64, 1); STAGE_B(64, 1);
    asm volatile("s_waitcnt vmcnt(4)" ::: "memory");
  } else {
    asm volatile("s_waitcnt vmcnt(0)" ::: "memory");
  }
  BARRIER();

  int cur = 0;
  for (int t = 0; t < nk; ++t) {
    const int kk2 = (t + 2) << 6;
    int idx2 = cur + 2; if (idx2 >= 3) idx2 -= 3;
    const char* base = smem[cur];

    // ---- phase 0: issue A(t+2), counted wait, barrier, frags, 8 MFMA
    if (t + 2 < nk) {
      STAGE_A(kk2, idx2);
      asm volatile("s_waitcnt vmcnt(6)" ::: "memory");
    } else if (t + 1 < nk) {
      asm volatile("s_waitcnt vmcnt(4)" ::: "memory");
    } else {
      asm volatile("s_waitcnt vmcnt(0)" ::: "memory");
    }
    BARRIER();
    a_[0] = *(const v4i*)(base + offA);
    a_[1] = *(const v4i*)(base + offA + 1024);
    a_[2] = *(const v4i*)(base + offA + 2048);
    a_[3] = *(const v4i*)(base + offA + 3072);
    b_[0] = *(const v4i*)(base + offB);
    b_[1] = *(const v4i*)(base + offB + 1024);
    __builtin_amdgcn_s_setprio(1);
    acc[0][0] = __builtin_amdgcn_mfma_i32_16x16x64_i8(a_[0], b_[0], acc[0][0], 0, 0, 0);
    acc[0][1] = __builtin_amdgcn_mfma_i32_16x16x64_i8(a_[0], b_[1], acc[0][1], 0, 0, 0);
    acc[1][0] = __builtin_amdgcn_mfma_i32_16x16x64_i8(a_[1], b_[0], acc[1][0], 0, 0, 0);
    acc[1][1] = __builtin_amdgcn_mfma_i32_16x16x64_i8(a_[1], b_[1], acc[1][1], 0, 0, 0);
    acc[2][0] = __builtin_amdgcn_mfma_i32_16x16x64_i8(a_[2], b_[0], acc[2][0], 0, 0, 0);
    acc[2][1] = __builtin_amdgcn_mfma_i32_16x16x64_i8(a_[2], b_[1], acc[2][1], 0, 0, 0);
    acc[3][0] = __builtin_amdgcn_mfma_i32_16x16x64_i8(a_[3], b_[0], acc[3][0], 0, 0, 0);
    acc[3][1] = __builtin_amdgcn_mfma_i32_16x16x64_i8(a_[3], b_[1], acc[3][1], 0, 0, 0);
    __builtin_amdgcn_s_setprio(0);
    BARRIER();

    // ---- phase 1: issue B(t+2), frags a4-7, 8 MFMA
    if (t + 2 < nk) STAGE_B(kk2, idx2);
    a_[4] = *(const v4i*)(base + offA + 4096);
    a_[5] = *(const v4i*)(base + offA + 5120);
    a_[6] = *(const v4i*)(base + offA + 6144);
    a_[7] = *(const v4i*)(base + offA + 7168);
    __builtin_amdgcn_s_setprio(1);
    acc[4][0] = __builtin_amdgcn_mfma_i32_16x16x64_i8(a_[4], b_[0], acc[4][0], 0, 0, 0);
    acc[4][1] = __builtin_amdgcn_mfma_i32_16x16x64_i8(a_[4], b_[1], acc[4][1], 0, 0, 0);
    acc[5][0] = __builtin_amdgcn_mfma_i32_16x16x64_i8(a_[5], b_[0], acc[5][0], 0, 0, 0);
    acc[5][1] = __builtin_amdgcn_mfma_i32_16x16x64_i8(a_[5], b_[1], acc[5][1], 0, 0, 0);
    acc[6][0] = __builtin_amdgcn_mfma_i32_16x16x64_i8(a_[6], b_[0], acc[6][0], 0, 0, 0);
    acc[6][1] = __builtin_amdgcn_mfma_i32_16x16x64_i8(a_[6], b_[1], acc[6][1], 0, 0, 0);
    acc[7][0] = __builtin_amdgcn_mfma_i32_16x16x64_i8(a_[7], b_[0], acc[7][0], 0, 0, 0);
    acc[7][1] = __builtin_amdgcn_mfma_i32_16x16x64_i8(a_[7], b_[1], acc[7][1], 0, 0, 0);
    __builtin_amdgcn_s_setprio(0);
    BARRIER();

    // ---- phase 2: frags b2-3, 8 MFMA
    b_[2] = *(const v4i*)(base + offB + 2048);
    b_[3] = *(const v4i*)(base + offB + 3072);
    __builtin_amdgcn_s_setprio(1);
    acc[0][2] = __builtin_amdgcn_mfma_i32_16x16x64_i8(a_[0], b_[2], acc[0][2], 0, 0, 0);
    acc[0][3] = __builtin_amdgcn_mfma_i32_16x16x64_i8(a_[0], b_[3], acc[0][3], 0, 0, 0);
    acc[1][2] = __builtin_amdgcn_mfma_i32_16x16x64_i8(a_[1], b_[2], acc[1][2], 0, 0, 0);
    acc[1][3] = __builtin_amdgcn_mfma_i32_16x16x64_i8(a_[1], b_[3], acc[1][3], 0, 0, 0);
    acc[2][2] = __builtin_amdgcn_mfma_i32_16x16x64_i8(a_[2], b_[2], acc[2][2], 0, 0, 0);
    acc[2][3] = __builtin_amdgcn_mfma_i32_16x16x64_i8(a_[2], b_[3], acc[2][3], 0, 0, 0);
    acc[3][2] = __builtin_amdgcn_mfma_i32_16x16x64_i8(a_[3], b_[2], acc[3][2], 0, 0, 0);
    acc[3][3] = __builtin_amdgcn_mfma_i32_16x16x64_i8(a_[3], b_[3], acc[3][3], 0, 0, 0);
    __builtin_amdgcn_s_setprio(0);
    BARRIER();

    // ---- phase 3: 8 MFMA
    __builtin_amdgcn_s_setprio(1);
    acc[4][2] = __builtin_amdgcn_mfma_i32_16x16x64_i8(a_[4], b_[2], acc[4][2], 0, 0, 0);
    acc[4][3] = __builtin_amdgcn_mfma_i32_16x16x64_i8(a_[4], b_[3], acc[4][3], 0, 0, 0);
    acc[5][2] = __builtin_amdgcn_mfma_i32_16x16x64_i8(a_[5], b_[2], acc[5][2], 0, 0, 0);
    acc[5][3] = __builtin_amdgcn_mfma_i32_16x16x64_i8(a_[5], b_[3], acc[5][3], 0, 0, 0);
    acc[6][2] = __builtin_amdgcn_mfma_i32_16x16x64_i8(a_[6], b_[2], acc[6][2], 0, 0, 0);
    acc[6][3] = __builtin_amdgcn_mfma_i32_16x16x64_i8(a_[6], b_[3], acc[6][3], 0, 0, 0);
    acc[7][2] = __builtin_amdgcn_mfma_i32_16x16x64_i8(a_[7], b_[2], acc[7][2], 0, 0, 0);
    acc[7][3] = __builtin_amdgcn_mfma_i32_16x16x64_i8(a_[7], b_[3], acc[7][3], 0, 0, 0);
    __builtin_amdgcn_s_setprio(0);
    BARRIER();

    cur += 1; if (cur >= 3) cur = 0;
  }
#undef STAGE_A
#undef STAGE_B

  // ---- epilogue
  long long cidx[4]; float w4[4], bi4[4]; bool cok[4];
#pragma unroll
  for (int ni = 0; ni < 4; ++ni) {
    cidx[ni] = n0 + waven * 64 + ni * 16 + lh;
    cok[ni] = cidx[ni] < N;
    w4[ni] = cok[ni] ? wsc[cidx[ni]] : 0.f;
    bi4[ni] = cok[ni] ? bias[cidx[ni]] : 0.f;
  }
  if (EPI == 0) {
#pragma unroll
    for (int mi = 0; mi < 8; ++mi) {
#pragma unroll
      for (int j = 0; j < 4; ++j) {
        const long long t = t0 + wavem * 128 + mi * 16 + (lane >> 4) * 4 + j;
        const bool valid = t < M;
        const float st = valid ? scale_tok[t] : 0.f;
        float rowmax = 0.f;
#pragma unroll
        for (int ni = 0; ni < 4; ++ni) {
          float v = (float)acc[mi][ni][j] * st * w4[ni] + bi4[ni];
          v = __half2float(__float2half(v));  // fc1 rounds to fp16 (reference)
          const float gl = 0.5f * v * (1.f + erff(v * 0.70710678118654752f));
          rowmax = fmaxf(rowmax, fabsf(gl));
          if (valid && cok[ni]) gout[t * (long long)N + cidx[ni]] = __float2half(gl);
        }
#pragma unroll
        for (int m = 1; m < 16; m <<= 1) rowmax = fmaxf(rowmax, __shfl_xor(rowmax, m));
        if (valid && lh == 0) atomicMax(&amax[t], __float_as_uint(rowmax));
      }
    }
  } else {
#pragma unroll
    for (int mi = 0; mi < 8; ++mi) {
#pragma unroll
      for (int j = 0; j < 4; ++j) {
        const long long t = t0 + wavem * 128 + mi * 16 + (lane >> 4) * 4 + j;
        if (t < M) {
          const float am = __uint_as_float(amax[t]);
          const float st = __half2float(__float2half(am * (1.f / 127.f)));
#pragma unroll
          for (int ni = 0; ni < 4; ++ni) {
            const float v = (float)acc[mi][ni][j] * st * w4[ni] + bi4[ni];
            if (cok[ni]) fout[t * (long long)N + cidx[ni]] = __half2float(__float2half(v));
          }
        }
      }
    }
  }
}

// ---------------------------------------------------------------------------
// int32 -> int8 packing for x, w1, w2 (+ zero the amax buffer each call)
// ---------------------------------------------------------------------------
__global__ void pack_all(const int* __restrict__ a, const int* __restrict__ b,
                         const int* __restrict__ c,
                         signed char* __restrict__ pa, signed char* __restrict__ pb,
                         signed char* __restrict__ pc,
                         unsigned int* __restrict__ amax,
                         long long na, long long nb, long long nc, int T) {
  const long long gid = blockIdx.x * (long long)blockDim.x + threadIdx.x;
  if (gid < T) amax[gid] = 0u;
  const long long n4a = na >> 2, n4b = nb >> 2, n4c = nc >> 2;
  const long long tot = n4a + n4b + n4c;
  const long long stride = (long long)gridDim.x * blockDim.x;
  for (long long u = gid; u < tot; u += stride) {
    const int* src; signed char* dst; long long loc;
    if (u < n4a)            { src = a; dst = pa; loc = u; }
    else if (u < n4a + n4b) { src = b; dst = pb; loc = u - n4a; }
    else                    { src = c; dst = pc; loc = u - n4a - n4b; }
    const int4 v = *(const int4*)(src + (loc << 2));
    const unsigned out = (unsigned)(v.x & 0xff) | ((unsigned)(v.y & 0xff) << 8) |
                         ((unsigned)(v.z & 0xff) << 16) | ((unsigned)(v.w & 0xff) << 24);
    *(unsigned*)(dst + (loc << 2)) = out;
  }
}

// ---------------------------------------------------------------------------
// per-token dynamic int8 quantization of the GELU output
// ---------------------------------------------------------------------------
__global__ void gelu_quant(const __half* __restrict__ g, const unsigned int* __restrict__ amax,
                           signed char* __restrict__ q, long long total, int I) {
  const long long nchunk = total >> 3;
  const long long stride = (long long)gridDim.x * blockDim.x;
  for (long long c = blockIdx.x * (long long)blockDim.x + threadIdx.x; c < nchunk; c += stride) {
    const long long base = c << 3;  // 8 elems, never crosses a row (I % 8 == 0)
    const int t = (int)(base / I);
    const float am = __uint_as_float(amax[t]);
    const float s = fmaxf(__half2float(__float2half(am * (1.f / 127.f))), 1e-8f);
    const float inv = 1.f / s;
    const int4 raw = *(const int4*)(g + base);
    const __half2* h2 = (const __half2*)&raw;
    union { signed char b[8]; int2 v; } u;
#pragma unroll
    for (int k = 0; k < 4; ++k) {
      const float2 f = __half22float2(h2[k]);
      const float q0 = fminf(fmaxf(rintf(f.x * inv), -128.f), 127.f);
      const float q1 = fminf(fmaxf(rintf(f.y * inv), -128.f), 127.f);
      u.b[k * 2]     = (signed char)(int)q0;
      u.b[k * 2 + 1] = (signed char)(int)q1;
    }
    *(int2*)(q + base) = u.v;
  }
}

extern "C" void kernel_launch(void* const* d_in, const int* in_sizes, int n_in,
                              void* d_out, int out_size, void* d_ws, size_t ws_size,
                              hipStream_t stream) {
  const int* hs = (const int*)d_in[0];
  const float* scale_in = (const float*)d_in[1];   // fp16 in reference -> f32 buffer
  const int* w1 = (const int*)d_in[2];
  const float* w1s = (const float*)d_in[3];
  const float* b1 = (const float*)d_in[4];
  const int* w2 = (const int*)d_in[5];
  const float* w2s = (const float*)d_in[6];
  const float* b2 = (const float*)d_in[7];

  const int T = in_sizes[1];        // 2050
  const int I = in_sizes[3];        // 12800
  const int H = in_sizes[6];        // 3200

  char* ws = (char*)d_ws;
  unsigned int* amax = (unsigned int*)ws;                    // T u32 (16KB pad)
  signed char* px  = (signed char*)(ws + 16384);             // T*H
  signed char* pw1 = px + (size_t)T * H;                     // I*H
  signed char* pw2 = pw1 + (size_t)I * H;                    // H*I
  __half* gbuf = (__half*)(pw2 + (size_t)H * I);             // T*I fp16
  signed char* qbuf = (signed char*)(gbuf + (size_t)T * I);  // T*I

  const long long nx = (long long)T * H, nw1 = (long long)I * H, nw2 = (long long)H * I;

  pack_all<<<2048, 256, 0, stream>>>(hs, w1, w2, px, pw1, pw2, amax, nx, nw1, nw2, T);

  dim3 g1(I / 256, (T + 255) / 256);
  gemm_i8_big<0><<<g1, 512, 0, stream>>>(px, pw1, T, I, H, scale_in, w1s, b1, gbuf, amax, nullptr);

  gelu_quant<<<2048, 256, 0, stream>>>(gbuf, amax, qbuf, (long long)T * I, I);

  dim3 g2((H + 255) / 256, (T + 255) / 256);
  gemm_i8_big<1><<<g2, 512, 0, stream>>>(qbuf, pw2, T, H, I, nullptr, w2s, b2, nullptr, amax, (float*)d_out);
}

// Round 4
// 404.072 us; speedup vs baseline: 1.1631x; 1.1631x over previous
//
#include <hip/hip_runtime.h>
#include <hip/hip_fp16.h>

typedef int v4i __attribute__((ext_vector_type(4)));

#define AS1C(p) ((const __attribute__((address_space(1))) void*)(p))
#define AS3(p)  ((__attribute__((address_space(3))) void*)(p))
#define BARRIER() do { __builtin_amdgcn_s_barrier(); asm volatile("" ::: "memory"); } while (0)

// ---------------------------------------------------------------------------
// Tiled int8 GEMM, C = A[M,K] * B[N,K]^T. BN=256 fixed, BM templated (256/128).
// 8 waves: 2M x 4N (wave tile BM/2 x 64). mfma_i32_16x16x64_i8, BK=64B.
// 3-buffer LDS ring, 1 half-tile staged per phase, counted vmcnt (4 or 3),
// template phase order: reads -> stage -> midBAR -> setprio+MFMA -> trailBAR.
// LDS 16B-slot XOR swizzle (involution; 0 conflicts measured in r2/r3).
// EPI 0: fc1 (dequant+bias -> fp16 -> GELU -> gout fp16 + atomicMax amax)
// EPI 1: fc2 (dequant with fp16(amax/127)+bias -> fp16-rounded f32 out)
// ---------------------------------------------------------------------------
template <int EPI, int BM>
__launch_bounds__(512, 2)
__global__ void gemm_tpl(const signed char* __restrict__ A, const signed char* __restrict__ Bw,
                         int M, int N, int K,
                         const float* __restrict__ scale_tok, const float* __restrict__ wsc,
                         const float* __restrict__ bias,
                         __half* __restrict__ gout, unsigned int* __restrict__ amax,
                         float* __restrict__ fout) {
  constexpr int ABYTES = BM * 64;          // A tile bytes (16K / 8K)
  constexpr int BUF = ABYTES + 16384;      // + B tile 16K
  constexpr int MI = BM / 32;              // m-frags per wave (8 / 4)
  constexpr int AH = BM / 128;             // A half-tiles (2 / 1)
  __shared__ __align__(16) char smem[3 * BUF];

  const int tid = threadIdx.x;
  const int lane = tid & 63, wave = tid >> 6;
  const int wavem = wave >> 2, waven = wave & 3;

  // bijective XCD-aware swizzle of the linear block id (m204 form)
  const int gx = gridDim.x;
  int lid = blockIdx.y * gx + blockIdx.x;
  {
    const int nwg = gx * gridDim.y;
    const int q = nwg >> 3, r = nwg & 7;
    const int x = lid & 7, p = lid >> 3;
    lid = (x < r ? x * (q + 1) : r * (q + 1) + (x - r) * q) + p;
  }
  const long long t0 = (long long)(lid / gx) * BM;
  const long long n0 = (long long)(lid % gx) * 256;
  const int nk = K >> 6;

  // ---- staging addresses (global side carries slot XOR; LDS linear)
  const int gs = (((lane & 3) ^ ((lane >> 3) & 3)) << 4);
  const long long Mm1 = M - 1, Nm1 = N - 1;
  const long long rA = t0 + wave * 16 + (lane >> 2);
  const long long rB = n0 + wave * 16 + (lane >> 2);
  const signed char* pa0 = A + (rA > Mm1 ? Mm1 : rA) * K + gs;
  const signed char* pa1 = nullptr;
  if constexpr (AH == 2) {
    const long long r2 = rA + 128;
    pa1 = A + (r2 > Mm1 ? Mm1 : r2) * K + gs;
  }
  const long long rB1 = rB + 128;
  const signed char* pb0 = Bw + (rB > Nm1 ? Nm1 : rB) * K + gs;
  const signed char* pb1 = Bw + (rB1 > Nm1 ? Nm1 : rB1) * K + gs;
  const int dA = wave * 1024;

#define SA0(kk, bi) __builtin_amdgcn_global_load_lds(AS1C(pa0 + (kk)), AS3(&smem[(bi) * BUF + dA]), 16, 0, 0)
#define SA1(kk, bi) __builtin_amdgcn_global_load_lds(AS1C(pa1 + (kk)), AS3(&smem[(bi) * BUF + 8192 + dA]), 16, 0, 0)
#define SB0(kk, bi) __builtin_amdgcn_global_load_lds(AS1C(pb0 + (kk)), AS3(&smem[(bi) * BUF + ABYTES + dA]), 16, 0, 0)
#define SB1(kk, bi) __builtin_amdgcn_global_load_lds(AS1C(pb1 + (kk)), AS3(&smem[(bi) * BUF + ABYTES + 8192 + dA]), 16, 0, 0)

  // ---- reader offsets (same XOR involution)
  const int lh = lane & 15;
  const int xs = (((lane >> 4) ^ ((lh >> 1) & 3)) << 4);
  const int offA = wavem * (BM / 2) * 64 + lh * 64 + xs;   // + mi*1024
  const int offB = ABYTES + waven * 4096 + lh * 64 + xs;   // + ni*1024

  v4i acc[MI][4] = {};
  v4i a_[MI], b_[4];

#define MFMA(mi, ni) acc[mi][ni] = __builtin_amdgcn_mfma_i32_16x16x64_i8(a_[mi], b_[ni], acc[mi][ni], 0, 0, 0)

  // ---- prologue: stage tiles 0 and 1, wait tile 0, barrier
  if constexpr (AH == 2) { SA0(0, 0); SA1(0, 0); } else { SA0(0, 0); }
  SB0(0, 0); SB1(0, 0);
  if (nk > 1) {
    if constexpr (AH == 2) { SA0(64, 1); SA1(64, 1); } else { SA0(64, 1); }
    SB0(64, 1); SB1(64, 1);
    if constexpr (AH == 2) asm volatile("s_waitcnt vmcnt(4)" ::: "memory");
    else                   asm volatile("s_waitcnt vmcnt(3)" ::: "memory");
  } else {
    asm volatile("s_waitcnt vmcnt(0)" ::: "memory");
  }
  BARRIER();

  int cur = 0;
  for (int t = 0; t < nk; ++t) {
    const char* base = &smem[cur * BUF];
    int b2 = cur + 2; if (b2 >= 3) b2 -= 3;
    const int kk2 = (t + 2) << 6;
    const bool pf = (t + 2) < nk;

    if constexpr (AH == 2) {
      // ---- P0: reads a0-3,b0-1 | stage A-h0(t+2) | bar | 8 MFMA | bar
      a_[0] = *(const v4i*)(base + offA);
      a_[1] = *(const v4i*)(base + offA + 1024);
      a_[2] = *(const v4i*)(base + offA + 2048);
      a_[3] = *(const v4i*)(base + offA + 3072);
      b_[0] = *(const v4i*)(base + offB);
      b_[1] = *(const v4i*)(base + offB + 1024);
      if (pf) SA0(kk2, b2);
      BARRIER();
      __builtin_amdgcn_s_setprio(1);
      MFMA(0, 0); MFMA(0, 1); MFMA(1, 0); MFMA(1, 1);
      MFMA(2, 0); MFMA(2, 1); MFMA(3, 0); MFMA(3, 1);
      __builtin_amdgcn_s_setprio(0);
      BARRIER();
      // ---- P1: reads a4-7 | stage A-h1 | bar | 8 MFMA | bar
      a_[4] = *(const v4i*)(base + offA + 4096);
      a_[5] = *(const v4i*)(base + offA + 5120);
      a_[6] = *(const v4i*)(base + offA + 6144);
      a_[7] = *(const v4i*)(base + offA + 7168);
      if (pf) SA1(kk2, b2);
      BARRIER();
      __builtin_amdgcn_s_setprio(1);
      MFMA(4, 0); MFMA(4, 1); MFMA(5, 0); MFMA(5, 1);
      MFMA(6, 0); MFMA(6, 1); MFMA(7, 0); MFMA(7, 1);
      __builtin_amdgcn_s_setprio(0);
      BARRIER();
      // ---- P2: reads b2-3 | stage B-h0 | bar | 8 MFMA | bar
      b_[2] = *(const v4i*)(base + offB + 2048);
      b_[3] = *(const v4i*)(base + offB + 3072);
      if (pf) SB0(kk2, b2);
      BARRIER();
      __builtin_amdgcn_s_setprio(1);
      MFMA(0, 2); MFMA(0, 3); MFMA(1, 2); MFMA(1, 3);
      MFMA(2, 2); MFMA(2, 3); MFMA(3, 2); MFMA(3, 3);
      __builtin_amdgcn_s_setprio(0);
      BARRIER();
      // ---- P3: stage B-h1 | vmcnt | bar | 8 MFMA | bar
      if (pf) { SB1(kk2, b2); asm volatile("s_waitcnt vmcnt(4)" ::: "memory"); }
      else    { asm volatile("s_waitcnt vmcnt(0)" ::: "memory"); }
      BARRIER();
      __builtin_amdgcn_s_setprio(1);
      MFMA(4, 2); MFMA(4, 3); MFMA(5, 2); MFMA(5, 3);
      MFMA(6, 2); MFMA(6, 3); MFMA(7, 2); MFMA(7, 3);
      __builtin_amdgcn_s_setprio(0);
      BARRIER();
    } else {
      // ---- P0: reads a0-3,b0-1 | stage A + B-h0 | bar | 8 MFMA | bar
      a_[0] = *(const v4i*)(base + offA);
      a_[1] = *(const v4i*)(base + offA + 1024);
      a_[2] = *(const v4i*)(base + offA + 2048);
      a_[3] = *(const v4i*)(base + offA + 3072);
      b_[0] = *(const v4i*)(base + offB);
      b_[1] = *(const v4i*)(base + offB + 1024);
      if (pf) { SA0(kk2, b2); SB0(kk2, b2); }
      BARRIER();
      __builtin_amdgcn_s_setprio(1);
      MFMA(0, 0); MFMA(0, 1); MFMA(1, 0); MFMA(1, 1);
      MFMA(2, 0); MFMA(2, 1); MFMA(3, 0); MFMA(3, 1);
      __builtin_amdgcn_s_setprio(0);
      BARRIER();
      // ---- P1: reads b2-3 | stage B-h1 | vmcnt | bar | 8 MFMA | bar
      b_[2] = *(const v4i*)(base + offB + 2048);
      b_[3] = *(const v4i*)(base + offB + 3072);
      if (pf) { SB1(kk2, b2); asm volatile("s_waitcnt vmcnt(3)" ::: "memory"); }
      else    { asm volatile("s_waitcnt vmcnt(0)" ::: "memory"); }
      BARRIER();
      __builtin_amdgcn_s_setprio(1);
      MFMA(0, 2); MFMA(0, 3); MFMA(1, 2); MFMA(1, 3);
      MFMA(2, 2); MFMA(2, 3); MFMA(3, 2); MFMA(3, 3);
      __builtin_amdgcn_s_setprio(0);
      BARRIER();
    }
    cur += 1; if (cur >= 3) cur = 0;
  }
#undef SA0
#undef SA1
#undef SB0
#undef SB1
#undef MFMA

  // ---- epilogue
  long long cidx[4]; float w4[4], bi4[4]; bool cok[4];
#pragma unroll
  for (int ni = 0; ni < 4; ++ni) {
    cidx[ni] = n0 + waven * 64 + ni * 16 + lh;
    cok[ni] = cidx[ni] < N;
    w4[ni] = cok[ni] ? wsc[cidx[ni]] : 0.f;
    bi4[ni] = cok[ni] ? bias[cidx[ni]] : 0.f;
  }
  if (EPI == 0) {
#pragma unroll
    for (int mi = 0; mi < MI; ++mi) {
#pragma unroll
      for (int j = 0; j < 4; ++j) {
        const long long t = t0 + wavem * (BM / 2) + mi * 16 + (lane >> 4) * 4 + j;
        const bool valid = t < M;
        const float st = valid ? scale_tok[t] : 0.f;
        float rowmax = 0.f;
#pragma unroll
        for (int ni = 0; ni < 4; ++ni) {
          float v = (float)acc[mi][ni][j] * st * w4[ni] + bi4[ni];
          v = __half2float(__float2half(v));  // fc1 rounds to fp16 (reference)
          const float gl = 0.5f * v * (1.f + erff(v * 0.70710678118654752f));
          rowmax = fmaxf(rowmax, fabsf(gl));
          if (valid && cok[ni]) gout[t * (long long)N + cidx[ni]] = __float2half(gl);
        }
#pragma unroll
        for (int m = 1; m < 16; m <<= 1) rowmax = fmaxf(rowmax, __shfl_xor(rowmax, m));
        if (valid && lh == 0) atomicMax(&amax[t], __float_as_uint(rowmax));
      }
    }
  } else {
#pragma unroll
    for (int mi = 0; mi < MI; ++mi) {
#pragma unroll
      for (int j = 0; j < 4; ++j) {
        const long long t = t0 + wavem * (BM / 2) + mi * 16 + (lane >> 4) * 4 + j;
        if (t < M) {
          const float am = __uint_as_float(amax[t]);
          const float st = __half2float(__float2half(am * (1.f / 127.f)));
#pragma unroll
          for (int ni = 0; ni < 4; ++ni) {
            const float v = (float)acc[mi][ni][j] * st * w4[ni] + bi4[ni];
            if (cok[ni]) fout[t * (long long)N + cidx[ni]] = __half2float(__float2half(v));
          }
        }
      }
    }
  }
}

// ---------------------------------------------------------------------------
// int32 -> int8 packing for x, w1, w2 (+ zero the amax buffer each call)
// ---------------------------------------------------------------------------
__global__ void pack_all(const int* __restrict__ a, const int* __restrict__ b,
                         const int* __restrict__ c,
                         signed char* __restrict__ pa, signed char* __restrict__ pb,
                         signed char* __restrict__ pc,
                         unsigned int* __restrict__ amax,
                         long long na, long long nb, long long nc, int T) {
  const long long gid = blockIdx.x * (long long)blockDim.x + threadIdx.x;
  if (gid < T) amax[gid] = 0u;
  const long long n4a = na >> 2, n4b = nb >> 2, n4c = nc >> 2;
  const long long tot = n4a + n4b + n4c;
  const long long stride = (long long)gridDim.x * blockDim.x;
  for (long long u = gid; u < tot; u += stride) {
    const int* src; signed char* dst; long long loc;
    if (u < n4a)            { src = a; dst = pa; loc = u; }
    else if (u < n4a + n4b) { src = b; dst = pb; loc = u - n4a; }
    else                    { src = c; dst = pc; loc = u - n4a - n4b; }
    const int4 v = *(const int4*)(src + (loc << 2));
    const unsigned out = (unsigned)(v.x & 0xff) | ((unsigned)(v.y & 0xff) << 8) |
                         ((unsigned)(v.z & 0xff) << 16) | ((unsigned)(v.w & 0xff) << 24);
    *(unsigned*)(dst + (loc << 2)) = out;
  }
}

// ---------------------------------------------------------------------------
// per-token dynamic int8 quantization of the GELU output
// ---------------------------------------------------------------------------
__global__ void gelu_quant(const __half* __restrict__ g, const unsigned int* __restrict__ amax,
                           signed char* __restrict__ q, long long total, int I) {
  const long long nchunk = total >> 3;
  const long long stride = (long long)gridDim.x * blockDim.x;
  for (long long c = blockIdx.x * (long long)blockDim.x + threadIdx.x; c < nchunk; c += stride) {
    const long long base = c << 3;  // 8 elems, never crosses a row (I % 8 == 0)
    const int t = (int)(base / I);
    const float am = __uint_as_float(amax[t]);
    const float s = fmaxf(__half2float(__float2half(am * (1.f / 127.f))), 1e-8f);
    const float inv = 1.f / s;
    const int4 raw = *(const int4*)(g + base);
    const __half2* h2 = (const __half2*)&raw;
    union { signed char b[8]; int2 v; } u;
#pragma unroll
    for (int k = 0; k < 4; ++k) {
      const float2 f = __half22float2(h2[k]);
      const float q0 = fminf(fmaxf(rintf(f.x * inv), -128.f), 127.f);
      const float q1 = fminf(fmaxf(rintf(f.y * inv), -128.f), 127.f);
      u.b[k * 2]     = (signed char)(int)q0;
      u.b[k * 2 + 1] = (signed char)(int)q1;
    }
    *(int2*)(q + base) = u.v;
  }
}

extern "C" void kernel_launch(void* const* d_in, const int* in_sizes, int n_in,
                              void* d_out, int out_size, void* d_ws, size_t ws_size,
                              hipStream_t stream) {
  const int* hs = (const int*)d_in[0];
  const float* scale_in = (const float*)d_in[1];   // fp16 in reference -> f32 buffer
  const int* w1 = (const int*)d_in[2];
  const float* w1s = (const float*)d_in[3];
  const float* b1 = (const float*)d_in[4];
  const int* w2 = (const int*)d_in[5];
  const float* w2s = (const float*)d_in[6];
  const float* b2 = (const float*)d_in[7];

  const int T = in_sizes[1];        // 2050
  const int I = in_sizes[3];        // 12800
  const int H = in_sizes[6];        // 3200

  char* ws = (char*)d_ws;
  unsigned int* amax = (unsigned int*)ws;                    // T u32 (16KB pad)
  signed char* px  = (signed char*)(ws + 16384);             // T*H
  signed char* pw1 = px + (size_t)T * H;                     // I*H
  signed char* pw2 = pw1 + (size_t)I * H;                    // H*I
  __half* gbuf = (__half*)(pw2 + (size_t)H * I);             // T*I fp16
  signed char* qbuf = (signed char*)(gbuf + (size_t)T * I);  // T*I

  const long long nx = (long long)T * H, nw1 = (long long)I * H, nw2 = (long long)H * I;

  pack_all<<<2048, 256, 0, stream>>>(hs, w1, w2, px, pw1, pw2, amax, nx, nw1, nw2, T);

  // fc1: 256x256 tiles, grid 50 x 9 = 450 blocks
  dim3 g1(I / 256, (T + 255) / 256);
  gemm_tpl<0, 256><<<g1, 512, 0, stream>>>(px, pw1, T, I, H, scale_in, w1s, b1, gbuf, amax, nullptr);

  gelu_quant<<<2048, 256, 0, stream>>>(gbuf, amax, qbuf, (long long)T * I, I);

  // fc2: 128x256 tiles, grid 13 x 17 = 221 blocks (chip-filling)
  dim3 g2((H + 255) / 256, (T + 127) / 128);
  gemm_tpl<1, 128><<<g2, 512, 0, stream>>>(qbuf, pw2, T, H, I, nullptr, w2s, b2, nullptr, amax, (float*)d_out);
}